// Round 14
// baseline (813.596 us; speedup 1.0000x reference)
//
#include <hip/hip_runtime.h>
#include <hip/hip_bf16.h>

// ============================================================================
// RecurrentDecoder v21: 162-block persistent kernel, flag dataflow.
// v20c post-mortem: f16 dot2 att datapath WIN (735->690 steady, VALUBusy
// 17.3->13.8 as predicted). v21 attacks intra-hop serialization:
//  1. att h-read: per-slice FUSED poll+read. Thread tid<128's 8B read covers
//     exactly d-slice tid>>2, so it polls ONLY hdone[tid>>2] then reads.
//     Reads start as individual producers finish (was: poll-32 -> barrier ->
//     read); deletes one barrier.
//  2. Fused publish drain: vmcnt is per-wave and each publish is one wave
//     store instruction, so store + s_waitcnt vmcnt(0) inside the asm + lane0
//     flag replaces store -> block-wide __syncthreads -> flag. Trailing
//     publish barrier deleted on BOTH att and GRU. (v16 bundled this with
//     bad poll moves; isolated here with polls kept at v20c placement.)
//     Hazard audit: post-publish LDS buffers (cp/h16) not rewritten until
//     >=3 barriers into the next step, which the publishing wave joins.
// att 6->4 barriers/step, GRU 6->5. Everything else byte-identical v20c:
// f16 dot2 att datapath, step-unique hbf[65]/ctxb[64], plain cached consumer
// reads, 4-way e-split, shfl 8/16/32, GRU K=1024 WC[kt&7], s_sleep waitge.
// ============================================================================

#define LOG2E 1.4426950408889634f
#define FLAGS_MAGIC 0x13572468u
#define SMEM_BYTES 138752
#define NBLK 162

typedef __attribute__((ext_vector_type(8))) short bf8;
typedef __attribute__((ext_vector_type(4))) float f32x4;
typedef __attribute__((ext_vector_type(4))) unsigned u32x4;
typedef __attribute__((ext_vector_type(2))) __fp16 h2f;  // matches builtin V2h
typedef unsigned long long ull;

#define EX2(x) exp2f(x)
#define MFMA16(a, b, c) __builtin_amdgcn_mfma_f32_16x16x32_bf16(a, b, c, 0, 0, 0)

struct Params {
  const float* dec;
  const float* ali;
  const float* watt;
  const float* wih;
  const float* whh;
  const float* wmel;
  const float* bmel;
  const float* wgate;
  const float* bgate;
  float* out;
  unsigned* bar;  // [0]=magic [16]=p0cnt [32+16i]=hdone(32) [544+16j]=ctxdone(128)
  __hip_bfloat16* wihb;    // [1536][512]
  __hip_bfloat16* whhb;    // [1536][512]
  __hip_bfloat16* wmelgb;  // [96][768]
  __hip_bfloat16* seqb;    // [64][32][256]
  __hip_bfloat16* hbf;     // [65][32][512]   slot s = h(s), step-unique
  __hip_bfloat16* ctxb;    // [64][128][256]  slot s = ctx(s) (hb = q4*32+b)
  unsigned* wattp;         // [256][256] packed F16 pairs of W_att^T
};

__device__ __forceinline__ bf8 ldfrag(const __hip_bfloat16* p) { return *(const bf8*)p; }
__device__ __forceinline__ float sigm(float x) { return 1.0f / (1.0f + EX2(-x * LOG2E)); }
__device__ __forceinline__ float tanhfast(float x) {
  x = fminf(fmaxf(x, -15.0f), 15.0f);
  float e = EX2(x * (2.0f * LOG2E));
  return (e - 1.0f) / (e + 1.0f);
}
__device__ __forceinline__ float btof(unsigned v) { return __uint_as_float(v << 16); }
__device__ __forceinline__ unsigned short f2bfbits(float x) {
  __hip_bfloat16 h = __float2bfloat16(x);
  return *(unsigned short*)&h;
}
// f16 helpers (att datapath)
__device__ __forceinline__ unsigned short f2hbits(float x) {
  __fp16 h = (__fp16)x;
  return *(unsigned short*)&h;
}
__device__ __forceinline__ float h16tof(unsigned short u) {
  __fp16 h;
  *(unsigned short*)&h = u;
  return (float)h;
}
__device__ __forceinline__ h2f as_h2(unsigned u) {
  union { unsigned u; h2f h; } c;
  c.u = u;
  return c.h;
}
__device__ __forceinline__ unsigned pk2h(float a, float b) {
  union { h2f h; unsigned u; } c;
  c.h = __builtin_amdgcn_cvt_pkrtz(a, b);
  return c.u;
}
#define DOT2(a, b, c) __builtin_amdgcn_fdot2((a), (b), (c), false)

__device__ __forceinline__ unsigned sysld32(const unsigned* p) {
  return __hip_atomic_load(p, __ATOMIC_RELAXED, __HIP_MEMORY_SCOPE_SYSTEM);
}
__device__ __forceinline__ void sysst32(unsigned* p, unsigned v) {
  __hip_atomic_store(p, v, __ATOMIC_RELAXED, __HIP_MEMORY_SCOPE_SYSTEM);
}
// Wide write-through store + per-WAVE drain (vmcnt counts the whole wave's
// store): store-ack guaranteed before any following flag store in this wave.
__device__ __forceinline__ void sysst16_drain(void* dst, u32x4 v) {
  asm volatile("global_store_dwordx4 %0, %1, off sc0 sc1\n\ts_waitcnt vmcnt(0)"
               :: "v"(dst), "v"(v) : "memory");
}
__device__ __forceinline__ void waitge(unsigned* w, unsigned tgt) {
  while (sysld32(w) < tgt) __builtin_amdgcn_s_sleep(1);
}

__device__ __forceinline__ void p0bar(unsigned* bar) {
  __syncthreads();
  if (threadIdx.x == 0) {
    __builtin_amdgcn_fence(__ATOMIC_RELEASE, "agent");
    __hip_atomic_fetch_add(bar + 16, 1u, __ATOMIC_RELAXED, __HIP_MEMORY_SCOPE_SYSTEM);
    while (sysld32(bar + 16) < (unsigned)NBLK) __builtin_amdgcn_s_sleep(1);
    __builtin_amdgcn_fence(__ATOMIC_ACQUIRE, "agent");
  }
  __syncthreads();
}

// P0 conversion work for blocks 128..161 (wid in [0, 34*512))
__device__ __forceinline__ void p0a_worker(const Params& p, int wid) {
  for (int i = wid; i < 2252800; i += 17408) {
    if (i < 786432) {
      p.wihb[i] = __float2bfloat16(p.wih[i]);
    } else if (i < 1572864) {
      int j = i - 786432;
      p.whhb[j] = __float2bfloat16(p.whh[j]);
    } else if (i < 2097152) {
      int j = i - 1572864;
      int s = j >> 13;
      p.seqb[j] = (s == 0) ? __float2bfloat16(0.0f) : __float2bfloat16(p.dec[j - 8192]);
    } else if (i < 2170880) {
      int j = i - 2097152;
      int r = j / 768, c = j - r * 768;
      float v = (r < 80) ? p.wmel[j] : ((r == 80) ? p.wgate[c] : 0.0f);
      p.wmelgb[j] = __float2bfloat16(v);
    } else if (i < 2236416) {
      int j = i - 2170880;
      int kp = j >> 8, e = j & 255;
      unsigned lo = f2hbits(p.watt[e * 512 + 2 * kp]);
      unsigned hi = f2hbits(p.watt[e * 512 + 2 * kp + 1]);
      p.wattp[j] = lo | (hi << 16);
    } else {
      int j = i - 2236416;
      p.hbf[j] = __float2bfloat16(0.0f);  // hbf slot 0 = h(0) = 0
    }
  }
}

// Stage h[32][512] (row-major, PLAIN cached loads) into fragment-major LDS.
__device__ __forceinline__ void stage_h_frag(__hip_bfloat16* hA,
                                             const __hip_bfloat16* hsrc, int tid) {
  const int lm = tid & 15, lq = (tid >> 4) & 3, wq = tid >> 6;
  const int dst_in = (lq * 16 + lm) * 8;
  const int i0 = wq, i1 = 8 + wq, i2 = 16 + wq, i3 = 24 + wq;
  auto soff = [&](int idx) {
    return ((idx >> 4) * 16 + lm) * 512 + (idx & 15) * 32 + lq * 8;
  };
  u32x4 a = *(const u32x4*)(hsrc + soff(i0));
  u32x4 b = *(const u32x4*)(hsrc + soff(i1));
  u32x4 c = *(const u32x4*)(hsrc + soff(i2));
  u32x4 d = *(const u32x4*)(hsrc + soff(i3));
  u32x4* dst = (u32x4*)hA;
  dst[(i0 * 512 + dst_in) >> 3] = a;
  dst[(i1 * 512 + dst_in) >> 3] = b;
  dst[(i2 * 512 + dst_in) >> 3] = c;
  dst[(i3 * 512 + dst_in) >> 3] = d;
}
// Stage concat-ctx [b, k=q4*256+e] (src slot: [128][256], hb=q4*32+b) into
// fragment-major LDS (64 sections over K=1024). PLAIN cached loads.
__device__ __forceinline__ void stage_c4(__hip_bfloat16* cA,
                                         const __hip_bfloat16* csrc, int tid) {
  const int lm = tid & 15, lq = (tid >> 4) & 3, wq = tid >> 6;
  const int dst_in = (lq * 16 + lm) * 8;
  u32x4* dst = (u32x4*)cA;
  auto soff = [&](int idx) {
    int mt = idx >> 5, kt = idx & 31;
    int bb = mt * 16 + lm;
    int k = kt * 32 + lq * 8;
    return ((k >> 8) * 32 + bb) * 256 + (k & 255);
  };
#pragma unroll
  for (int r = 0; r < 8; ++r) {
    const int idx = r * 8 + wq;
    u32x4 v = *(const u32x4*)(csrc + soff(idx));
    dst[(idx * 512 + dst_in) >> 3] = v;
  }
}

__global__ void __launch_bounds__(512, 1) rdec_kernel(Params p) {
  const int tid = threadIdx.x;
  const int bid = blockIdx.x;
  extern __shared__ char smem[];
  unsigned* hdone = p.bar + 32;     // 32 flags
  unsigned* ctxdone = p.bar + 544;  // 128 flags

  if (bid == 0) {
    for (int i = 1 + tid; i < 2624; i += 512) sysst32(p.bar + i, 0u);
    __syncthreads();
    if (tid == 0) sysst32(p.bar, FLAGS_MAGIC);
  }

  if (bid < 128) {
    // =================== ATT path (batch b, e-quarter q4) ===================
    const int b = bid >> 2, q4 = bid & 3, hb = q4 * 32 + b;
    unsigned short* alds = (unsigned short*)smem;  // [256 f][260 t] F16 (pad)
    float* fb = (float*)(smem + 133120);
    float* shh = fb;          // 256 u32: h(s)[b,:] as packed f16 pairs
    float* p2l = fb + 512;    // 64    proj_e * LOG2E (my e-quarter)
    float* rzl = fb + 576;    // 64    1/Z_e
    float* tw = fb + 640;     // 128 u32: tw packed f16 pairs
    float* cp = fb + 896;     // [2][256] ctx partial reduce (fp32)

    // el in lane LOW bits (bank spread), kq in lane bits 3..5 (shfl 8/16/32)
    const int el = (tid & 7) | ((tid >> 6) << 3);  // e-local / t-quad (0..63)
    const int kq = (tid >> 3) & 7;                 // k-/t-eighth / e-group
    const int f = tid & 255, th = tid >> 8;        // ctx mapping

    // P0: full a[:,b,:] -> alds[f][t] as F16
    for (int i = tid; i < 65536; i += 512) {
      int t = i >> 8, ee = i & 255;
      alds[ee * 260 + t] = f2hbits(p.ali[t * 8192 + b * 256 + ee]);
    }
    if (tid == 0) {
      while (sysld32(p.bar) != FLAGS_MAGIC) __builtin_amdgcn_s_sleep(1);
    }
    p0bar(p.bar);
    // k-strided weight regs (f16 pairs): kp = i*8 + kq
    unsigned wr[32];
#pragma unroll
    for (int i = 0; i < 32; ++i) wr[i] = p.wattp[(i * 8 + kq) * 256 + q4 * 64 + el];

    for (int s = 0; s < 64; ++s) {
      // FUSED per-slice poll + read: thread's 8B covers d-slice tid>>2 only.
      // Reads start as individual GRU producers finish; one barrier total.
      if (tid < 128) {
        waitge(hdone + (tid >> 2) * 16, (unsigned)s);
        ull w = ((const ull*)(p.hbf + s * 16384 + b * 512))[tid];
        float f0 = btof((unsigned)(w & 0xffff));
        float f1 = btof((unsigned)((w >> 16) & 0xffff));
        float f2c = btof((unsigned)((w >> 32) & 0xffff));
        float f3 = btof((unsigned)((w >> 48) & 0xffff));
        unsigned* hp = (unsigned*)shh;
        hp[tid * 2] = pk2h(f0, f1);
        hp[tid * 2 + 1] = pk2h(f2c, f3);
      }
      __syncthreads();
      // proj (k-eighth, dot2) + Z (t-eighth) fused in-register, shfl 8/16/32
      {
        const unsigned* hp = (const unsigned*)shh;
        float a0 = 0.f, a1 = 0.f;
#pragma unroll
        for (int i = 0; i < 32; i += 2) {
          a0 = DOT2(as_h2(wr[i]), as_h2(hp[i * 8 + kq]), a0);
          a1 = DOT2(as_h2(wr[i + 1]), as_h2(hp[(i + 1) * 8 + kq]), a1);
        }
        float pr = a0 + a1;
        pr += __shfl_xor(pr, 8);
        pr += __shfl_xor(pr, 16);
        pr += __shfl_xor(pr, 32);
        const float pp = pr * LOG2E;
        // Z partial over my t-eighth (32 t)
        const unsigned short* ap = alds + (q4 * 64 + el) * 260 + kq * 32;
        float z0 = 0.f, z1 = 0.f;
#pragma unroll
        for (int j = 0; j < 8; ++j) {
          ushort4 v = *(const ushort4*)(ap + j * 4);
          z0 += EX2(h16tof(v.x) * pp) + EX2(h16tof(v.y) * pp);
          z1 += EX2(h16tof(v.z) * pp) + EX2(h16tof(v.w) * pp);
        }
        float zz = z0 + z1;
        zz += __shfl_xor(zz, 8);
        zz += __shfl_xor(zz, 16);
        zz += __shfl_xor(zz, 32);
        if (kq == 0) {
          p2l[el] = pp;
          rzl[el] = 1.0f / zz;
        }
      }
      __syncthreads();
      // pass2: tw_t = sum_e u/Z over my 64 e; shfl 8/16/32; writers pack f16
      {
        float t0 = 0.f, t1 = 0.f, t2 = 0.f, t3 = 0.f;
#pragma unroll
        for (int j = 0; j < 8; ++j) {
          const int e2 = kq * 8 + j;
          ushort4 v = *(const ushort4*)(alds + (q4 * 64 + e2) * 260 + el * 4);
          const float ppj = p2l[e2], rr = rzl[e2];
          t0 = fmaf(EX2(h16tof(v.x) * ppj), rr, t0);
          t1 = fmaf(EX2(h16tof(v.y) * ppj), rr, t1);
          t2 = fmaf(EX2(h16tof(v.z) * ppj), rr, t2);
          t3 = fmaf(EX2(h16tof(v.w) * ppj), rr, t3);
        }
        t0 += __shfl_xor(t0, 8); t0 += __shfl_xor(t0, 16); t0 += __shfl_xor(t0, 32);
        t1 += __shfl_xor(t1, 8); t1 += __shfl_xor(t1, 16); t1 += __shfl_xor(t1, 32);
        t2 += __shfl_xor(t2, 8); t2 += __shfl_xor(t2, 16); t2 += __shfl_xor(t2, 32);
        t3 += __shfl_xor(t3, 8); t3 += __shfl_xor(t3, 16); t3 += __shfl_xor(t3, 32);
        if (kq == 0) {
          unsigned* twp = (unsigned*)tw;
          twp[el * 2] = pk2h(t0, t1);
          twp[el * 2 + 1] = pk2h(t2, t3);
        }
      }
      __syncthreads();
      // ctx partial: ALL 256 f, t-half per th, dot2 (2 MAC/inst)
      {
        const unsigned short* ap = alds + f * 260 + th * 128;
        const unsigned* twv = (const unsigned*)tw + th * 64;
        float c0 = 0.f, c1 = 0.f;
#pragma unroll 4
        for (int j = 0; j < 32; ++j) {
          uint2 v = *(const uint2*)(ap + j * 4);
          c0 = DOT2(as_h2(v.x), as_h2(twv[2 * j]), c0);
          c1 = DOT2(as_h2(v.y), as_h2(twv[2 * j + 1]), c1);
        }
        cp[th * 256 + f] = c0 + c1;
      }
      __syncthreads();
      // FUSED publish: wave-0 lanes 0-31 pack + one dwordx4 store + per-wave
      // vmcnt drain; lane 0 posts flag. No trailing barrier (cp not rewritten
      // until >=3 barriers into the next step, which wave 0 joins).
      if (tid < 32) {
        const float4* cpa = (const float4*)cp + 2 * tid;
        const float4* cpb = (const float4*)(cp + 256) + 2 * tid;
        u32x4 u;
#pragma unroll
        for (int q = 0; q < 2; ++q) {
          float4 ca = cpa[q], cb = cpb[q];
          u[2 * q + 0] = (unsigned)f2bfbits(ca.x + cb.x) |
                         ((unsigned)f2bfbits(ca.y + cb.y) << 16);
          u[2 * q + 1] = (unsigned)f2bfbits(ca.z + cb.z) |
                         ((unsigned)f2bfbits(ca.w + cb.w) << 16);
        }
        sysst16_drain((unsigned*)(p.ctxb + (s * 128 + hb) * 256) + 4 * tid, u);
      }
      if (tid == 0) sysst32(ctxdone + hb * 16, (unsigned)(s + 1));
    }
  } else if (bid < 160) {
    // ============================ GRU path ============================
    const int dt = bid - 128;
    const int wv = tid >> 6;
    const bool act = wv < 6;
    const int l = tid & 63, lm = l & 15, lq = l >> 4;
    const int g = wv % 3, mt = wv / 3;
    const int am = mt * 16 + lm;
    const int brow = g * 512 + dt * 16 + lm;
    __hip_bfloat16* hA = (__hip_bfloat16*)smem;             // frag-major 32KB
    __hip_bfloat16* cA = (__hip_bfloat16*)(smem + 32768);   // frag-major 64KB (K=1024)
    float* pw = (float*)(smem + 98304);                     // [8][16][17]
    unsigned short* h16 = (unsigned short*)(smem + 107008); // [512]
    p0a_worker(p, (bid - 128) * 512 + tid);
    if (tid == 0) {
      while (sysld32(p.bar) != FLAGS_MAGIC) __builtin_amdgcn_s_sleep(1);
    }
    p0bar(p.bar);
    bf8 WH[16], WD[8], WC[8];
    if (act) {
#pragma unroll
      for (int kt = 0; kt < 16; ++kt) WH[kt] = ldfrag(p.whhb + brow * 512 + kt * 32 + lq * 8);
#pragma unroll
      for (int kt = 0; kt < 8; ++kt) WD[kt] = ldfrag(p.wihb + brow * 512 + kt * 32 + lq * 8);
#pragma unroll
      for (int kt = 0; kt < 8; ++kt) WC[kt] = ldfrag(p.wihb + brow * 512 + 256 + kt * 32 + lq * 8);
    }
    for (int s = 0; s < 64; ++s) {
      if (tid < 32) waitge(hdone + tid * 16, (unsigned)s);
      __syncthreads();
      stage_h_frag(hA, p.hbf + s * 16384, tid);
      __syncthreads();
      f32x4 acc = {0.f, 0.f, 0.f, 0.f};
      f32x4 gi = {0.f, 0.f, 0.f, 0.f};
      if (act) {
#pragma unroll
        for (int kt = 0; kt < 16; ++kt) {
          bf8 a = ldfrag(hA + (mt * 16 + kt) * 512 + l * 8);
          acc = MFMA16(a, WH[kt], acc);
        }
        const __hip_bfloat16* seqp = p.seqb + s * 8192;
#pragma unroll
        for (int kt = 0; kt < 8; ++kt) {
          bf8 a = ldfrag(seqp + am * 256 + kt * 32 + lq * 8);
          gi = MFMA16(a, WD[kt], gi);
        }
      }
      if (tid < 128) waitge(ctxdone + tid * 16, (unsigned)(s + 1));
      __syncthreads();
      stage_c4(cA, p.ctxb + s * 32768, tid);
      __syncthreads();
      if (act) {
        // gi_ctx over K=1024 concat quarters with duplicated W rows
#pragma unroll
        for (int kt = 0; kt < 32; ++kt) {
          bf8 a = ldfrag(cA + (mt * 32 + kt) * 512 + l * 8);
          gi = MFMA16(a, WC[kt & 7], gi);
        }
        if (g < 2) {
#pragma unroll
          for (int r = 0; r < 4; ++r) pw[(wv * 16 + lq * 4 + r) * 17 + lm] = acc[r] + gi[r];
        } else {
#pragma unroll
          for (int r = 0; r < 4; ++r) pw[(wv * 16 + lq * 4 + r) * 17 + lm] = acc[r];
#pragma unroll
          for (int r = 0; r < 4; ++r) pw[((6 + mt) * 16 + lq * 4 + r) * 17 + lm] = gi[r];
        }
      }
      __syncthreads();
      {
        const int bb = tid >> 4, dl = tid & 15;
        const int mtb = bb >> 4, bl = bb & 15;
        float rg = sigm(pw[((mtb * 3 + 0) * 16 + bl) * 17 + dl]);
        float zg = sigm(pw[((mtb * 3 + 1) * 16 + bl) * 17 + dl]);
        float hn = pw[((mtb * 3 + 2) * 16 + bl) * 17 + dl];
        float inn = pw[((6 + mtb) * 16 + bl) * 17 + dl];
        float nn = tanhfast(fmaf(rg, hn, inn));
        const int d = dt * 16 + dl;
        float ho = btof(((unsigned short*)hA)[((bb >> 4) * 16 + (d >> 5)) * 512 +
                                              (((d >> 3) & 3) * 16 + (bb & 15)) * 8 +
                                              (d & 7)]);
        float hnew = fmaxf(0.0f, fmaf(zg, ho - nn, nn));
        h16[bb * 16 + dl] = f2bfbits(hnew);
      }
      __syncthreads();
      // FUSED publish: wave 0 (64 lanes) x dwordx4 + per-wave drain; lane 0
      // posts flag. No trailing barrier (h16 not rewritten until >=3 barriers
      // into the next step, which wave 0 joins).
      if (tid < 64) {
        u32x4 hv = *(const u32x4*)(h16 + 8 * tid);
        sysst16_drain((unsigned*)(p.hbf + (s + 1) * 16384) +
                          (tid >> 1) * 256 + dt * 8 + (tid & 1) * 4,
                      hv);
      }
      if (tid == 0) sysst32(hdone + dt * 16, (unsigned)(s + 1));
    }
  } else {
    // ============================ MEL path ============================
    const int mt = bid - 160;  // batch half
    const int wv = tid >> 6;
    const bool act = wv < 6;
    const int l = tid & 63, lm = l & 15, lq = l >> 4;
    const int nt = wv;
    const int bn = nt * 16 + lm;
    __hip_bfloat16* hA = (__hip_bfloat16*)smem;
    __hip_bfloat16* cA = (__hip_bfloat16*)(smem + 32768);  // 64KB, K=1024
    p0a_worker(p, (bid - 128) * 512 + tid);
    if (tid == 0) {
      while (sysld32(p.bar) != FLAGS_MAGIC) __builtin_amdgcn_s_sleep(1);
    }
    p0bar(p.bar);
    bf8 WMC[8], WMH[16];
    float bias = 0.f;
    if (act) {
#pragma unroll
      for (int kt = 0; kt < 8; ++kt) WMC[kt] = ldfrag(p.wmelgb + bn * 768 + kt * 32 + lq * 8);
#pragma unroll
      for (int kt = 0; kt < 16; ++kt)
        WMH[kt] = ldfrag(p.wmelgb + bn * 768 + 256 + kt * 32 + lq * 8);
      bias = (bn < 80) ? p.bmel[bn] : ((bn == 80) ? p.bgate[0] : 0.f);
    }
    for (int tau = 0; tau < 64; ++tau) {
      if (tid < 32) waitge(hdone + tid * 16, (unsigned)(tau + 1));
      else if (tid >= 64 && tid < 192) waitge(ctxdone + (tid - 64) * 16, (unsigned)(tau + 1));
      __syncthreads();
      stage_h_frag(hA, p.hbf + (tau + 1) * 16384, tid);
      stage_c4(cA, p.ctxb + tau * 32768, tid);
      __syncthreads();
      if (act) {
        f32x4 acc = {0.f, 0.f, 0.f, 0.f};
#pragma unroll
        for (int kt = 0; kt < 48; ++kt) {
          bf8 a = (kt < 32) ? ldfrag(cA + (mt * 32 + kt) * 512 + l * 8)
                            : ldfrag(hA + (mt * 16 + (kt - 32)) * 512 + l * 8);
          bf8 bb2 = (kt < 32) ? WMC[kt & 7] : WMH[kt - 32];
          acc = MFMA16(a, bb2, acc);
        }
#pragma unroll
        for (int r = 0; r < 4; ++r) {
          int bb = mt * 16 + lq * 4 + r;
          float v = acc[r] + bias;
          if (bn < 80)
            p.out[bb * 5120 + bn * 64 + tau] = v;
          else if (bn == 80)
            p.out[163840 + bb * 64 + tau] = v;
        }
      }
      __syncthreads();
    }
  }
}

extern "C" void kernel_launch(void* const* d_in, const int* in_sizes, int n_in,
                              void* d_out, int out_size, void* d_ws, size_t ws_size,
                              hipStream_t stream) {
  Params P;
  P.dec = (const float*)d_in[0];
  P.ali = (const float*)d_in[1];
  P.watt = (const float*)d_in[2];
  P.wih = (const float*)d_in[3];
  P.whh = (const float*)d_in[4];
  P.wmel = (const float*)d_in[5];
  P.bmel = (const float*)d_in[6];
  P.wgate = (const float*)d_in[7];
  P.bgate = (const float*)d_in[8];
  P.out = (float*)d_out;

  char* w = (char*)d_ws;
  size_t o = 0;
  auto nxt = [&](size_t b) {
    char* r = w + o;
    o += (b + 255) & ~(size_t)255;
    return r;
  };
  P.bar = (unsigned*)nxt(16384);
  P.wihb = (__hip_bfloat16*)nxt(1536 * 512 * 2);
  P.whhb = (__hip_bfloat16*)nxt(1536 * 512 * 2);
  P.wmelgb = (__hip_bfloat16*)nxt(96 * 768 * 2);
  P.seqb = (__hip_bfloat16*)nxt(64 * 32 * 256 * 2);
  P.hbf = (__hip_bfloat16*)nxt(65 * 32 * 512 * 2);    // step-unique h ring
  P.ctxb = (__hip_bfloat16*)nxt(64 * 128 * 256 * 2);  // step-unique ctx ring
  P.wattp = (unsigned*)nxt(256 * 256 * 4);

  (void)hipFuncSetAttribute((const void*)rdec_kernel,
                            hipFuncAttributeMaxDynamicSharedMemorySize, SMEM_BYTES);

  void* args[] = {&P};
  hipError_t err = hipLaunchCooperativeKernel((void*)rdec_kernel, dim3(NBLK), dim3(512),
                                              args, SMEM_BYTES, stream);
  if (err != hipSuccess) {
    rdec_kernel<<<dim3(NBLK), dim3(512), SMEM_BYTES, stream>>>(P);
  }
}

// Round 15
// 813.348 us; speedup vs baseline: 1.0003x; 1.0003x over previous
//
#include <hip/hip_runtime.h>
#include <hip/hip_bf16.h>

// ============================================================================
// RecurrentDecoder v22: 162-block persistent kernel, flag dataflow.
// v21 post-mortem: REGRESSED 690->737. Bundle of 2; counters (pure stall,
// VALU/MFMA down proportionally) indict edit #1: per-slice fused poll+read
// put 128 lanes x 128 blocks on system-scope poll spins for the whole hdone
// wait (4x poll streams) -- the v16 wide-poll pathology (+0.73us/step here
// vs +1.15 there). Edit #2 (fused publish drain) was bundled and unmeasured.
// v22 = BISECT: v20c + fused publish ONLY.
//  - Polls restored to v20c placement: att tid<32 poll 32 hdone flags ->
//    barrier -> 128-lane h read. GRU polls unchanged.
//  - Publishes keep v21's per-wave drain: wide sc0sc1 store + in-asm
//    s_waitcnt vmcnt(0) + lane0 flag; trailing block barrier deleted on
//    both sides (att 6->5, GRU 6->5 barriers/step). Hazard: cp/h16 not
//    rewritten until >=3 barriers into next step; publishing wave joins.
// Everything else byte-identical v20c: f16 dot2 att datapath, step-unique
// hbf[65]/ctxb[64], plain cached consumer reads, 4-way e-split, shfl
// 8/16/32, GRU K=1024 WC[kt&7], s_sleep waitge, mel blocks 160/161.
// ============================================================================

#define LOG2E 1.4426950408889634f
#define FLAGS_MAGIC 0x13572468u
#define SMEM_BYTES 138752
#define NBLK 162

typedef __attribute__((ext_vector_type(8))) short bf8;
typedef __attribute__((ext_vector_type(4))) float f32x4;
typedef __attribute__((ext_vector_type(4))) unsigned u32x4;
typedef __attribute__((ext_vector_type(2))) __fp16 h2f;  // matches builtin V2h
typedef unsigned long long ull;

#define EX2(x) exp2f(x)
#define MFMA16(a, b, c) __builtin_amdgcn_mfma_f32_16x16x32_bf16(a, b, c, 0, 0, 0)

struct Params {
  const float* dec;
  const float* ali;
  const float* watt;
  const float* wih;
  const float* whh;
  const float* wmel;
  const float* bmel;
  const float* wgate;
  const float* bgate;
  float* out;
  unsigned* bar;  // [0]=magic [16]=p0cnt [32+16i]=hdone(32) [544+16j]=ctxdone(128)
  __hip_bfloat16* wihb;    // [1536][512]
  __hip_bfloat16* whhb;    // [1536][512]
  __hip_bfloat16* wmelgb;  // [96][768]
  __hip_bfloat16* seqb;    // [64][32][256]
  __hip_bfloat16* hbf;     // [65][32][512]   slot s = h(s), step-unique
  __hip_bfloat16* ctxb;    // [64][128][256]  slot s = ctx(s) (hb = q4*32+b)
  unsigned* wattp;         // [256][256] packed F16 pairs of W_att^T
};

__device__ __forceinline__ bf8 ldfrag(const __hip_bfloat16* p) { return *(const bf8*)p; }
__device__ __forceinline__ float sigm(float x) { return 1.0f / (1.0f + EX2(-x * LOG2E)); }
__device__ __forceinline__ float tanhfast(float x) {
  x = fminf(fmaxf(x, -15.0f), 15.0f);
  float e = EX2(x * (2.0f * LOG2E));
  return (e - 1.0f) / (e + 1.0f);
}
__device__ __forceinline__ float btof(unsigned v) { return __uint_as_float(v << 16); }
__device__ __forceinline__ unsigned short f2bfbits(float x) {
  __hip_bfloat16 h = __float2bfloat16(x);
  return *(unsigned short*)&h;
}
// f16 helpers (att datapath)
__device__ __forceinline__ unsigned short f2hbits(float x) {
  __fp16 h = (__fp16)x;
  return *(unsigned short*)&h;
}
__device__ __forceinline__ float h16tof(unsigned short u) {
  __fp16 h;
  *(unsigned short*)&h = u;
  return (float)h;
}
__device__ __forceinline__ h2f as_h2(unsigned u) {
  union { unsigned u; h2f h; } c;
  c.u = u;
  return c.h;
}
__device__ __forceinline__ unsigned pk2h(float a, float b) {
  union { h2f h; unsigned u; } c;
  c.h = __builtin_amdgcn_cvt_pkrtz(a, b);
  return c.u;
}
#define DOT2(a, b, c) __builtin_amdgcn_fdot2((a), (b), (c), false)

__device__ __forceinline__ unsigned sysld32(const unsigned* p) {
  return __hip_atomic_load(p, __ATOMIC_RELAXED, __HIP_MEMORY_SCOPE_SYSTEM);
}
__device__ __forceinline__ void sysst32(unsigned* p, unsigned v) {
  __hip_atomic_store(p, v, __ATOMIC_RELAXED, __HIP_MEMORY_SCOPE_SYSTEM);
}
// Wide write-through store + per-WAVE drain (vmcnt counts the whole wave's
// store): store-ack guaranteed before any following flag store in this wave.
__device__ __forceinline__ void sysst16_drain(void* dst, u32x4 v) {
  asm volatile("global_store_dwordx4 %0, %1, off sc0 sc1\n\ts_waitcnt vmcnt(0)"
               :: "v"(dst), "v"(v) : "memory");
}
__device__ __forceinline__ void waitge(unsigned* w, unsigned tgt) {
  while (sysld32(w) < tgt) __builtin_amdgcn_s_sleep(1);
}

__device__ __forceinline__ void p0bar(unsigned* bar) {
  __syncthreads();
  if (threadIdx.x == 0) {
    __builtin_amdgcn_fence(__ATOMIC_RELEASE, "agent");
    __hip_atomic_fetch_add(bar + 16, 1u, __ATOMIC_RELAXED, __HIP_MEMORY_SCOPE_SYSTEM);
    while (sysld32(bar + 16) < (unsigned)NBLK) __builtin_amdgcn_s_sleep(1);
    __builtin_amdgcn_fence(__ATOMIC_ACQUIRE, "agent");
  }
  __syncthreads();
}

// P0 conversion work for blocks 128..161 (wid in [0, 34*512))
__device__ __forceinline__ void p0a_worker(const Params& p, int wid) {
  for (int i = wid; i < 2252800; i += 17408) {
    if (i < 786432) {
      p.wihb[i] = __float2bfloat16(p.wih[i]);
    } else if (i < 1572864) {
      int j = i - 786432;
      p.whhb[j] = __float2bfloat16(p.whh[j]);
    } else if (i < 2097152) {
      int j = i - 1572864;
      int s = j >> 13;
      p.seqb[j] = (s == 0) ? __float2bfloat16(0.0f) : __float2bfloat16(p.dec[j - 8192]);
    } else if (i < 2170880) {
      int j = i - 2097152;
      int r = j / 768, c = j - r * 768;
      float v = (r < 80) ? p.wmel[j] : ((r == 80) ? p.wgate[c] : 0.0f);
      p.wmelgb[j] = __float2bfloat16(v);
    } else if (i < 2236416) {
      int j = i - 2170880;
      int kp = j >> 8, e = j & 255;
      unsigned lo = f2hbits(p.watt[e * 512 + 2 * kp]);
      unsigned hi = f2hbits(p.watt[e * 512 + 2 * kp + 1]);
      p.wattp[j] = lo | (hi << 16);
    } else {
      int j = i - 2236416;
      p.hbf[j] = __float2bfloat16(0.0f);  // hbf slot 0 = h(0) = 0
    }
  }
}

// Stage h[32][512] (row-major, PLAIN cached loads) into fragment-major LDS.
__device__ __forceinline__ void stage_h_frag(__hip_bfloat16* hA,
                                             const __hip_bfloat16* hsrc, int tid) {
  const int lm = tid & 15, lq = (tid >> 4) & 3, wq = tid >> 6;
  const int dst_in = (lq * 16 + lm) * 8;
  const int i0 = wq, i1 = 8 + wq, i2 = 16 + wq, i3 = 24 + wq;
  auto soff = [&](int idx) {
    return ((idx >> 4) * 16 + lm) * 512 + (idx & 15) * 32 + lq * 8;
  };
  u32x4 a = *(const u32x4*)(hsrc + soff(i0));
  u32x4 b = *(const u32x4*)(hsrc + soff(i1));
  u32x4 c = *(const u32x4*)(hsrc + soff(i2));
  u32x4 d = *(const u32x4*)(hsrc + soff(i3));
  u32x4* dst = (u32x4*)hA;
  dst[(i0 * 512 + dst_in) >> 3] = a;
  dst[(i1 * 512 + dst_in) >> 3] = b;
  dst[(i2 * 512 + dst_in) >> 3] = c;
  dst[(i3 * 512 + dst_in) >> 3] = d;
}
// Stage concat-ctx [b, k=q4*256+e] (src slot: [128][256], hb=q4*32+b) into
// fragment-major LDS (64 sections over K=1024). PLAIN cached loads.
__device__ __forceinline__ void stage_c4(__hip_bfloat16* cA,
                                         const __hip_bfloat16* csrc, int tid) {
  const int lm = tid & 15, lq = (tid >> 4) & 3, wq = tid >> 6;
  const int dst_in = (lq * 16 + lm) * 8;
  u32x4* dst = (u32x4*)cA;
  auto soff = [&](int idx) {
    int mt = idx >> 5, kt = idx & 31;
    int bb = mt * 16 + lm;
    int k = kt * 32 + lq * 8;
    return ((k >> 8) * 32 + bb) * 256 + (k & 255);
  };
#pragma unroll
  for (int r = 0; r < 8; ++r) {
    const int idx = r * 8 + wq;
    u32x4 v = *(const u32x4*)(csrc + soff(idx));
    dst[(idx * 512 + dst_in) >> 3] = v;
  }
}

__global__ void __launch_bounds__(512, 1) rdec_kernel(Params p) {
  const int tid = threadIdx.x;
  const int bid = blockIdx.x;
  extern __shared__ char smem[];
  unsigned* hdone = p.bar + 32;     // 32 flags
  unsigned* ctxdone = p.bar + 544;  // 128 flags

  if (bid == 0) {
    for (int i = 1 + tid; i < 2624; i += 512) sysst32(p.bar + i, 0u);
    __syncthreads();
    if (tid == 0) sysst32(p.bar, FLAGS_MAGIC);
  }

  if (bid < 128) {
    // =================== ATT path (batch b, e-quarter q4) ===================
    const int b = bid >> 2, q4 = bid & 3, hb = q4 * 32 + b;
    unsigned short* alds = (unsigned short*)smem;  // [256 f][260 t] F16 (pad)
    float* fb = (float*)(smem + 133120);
    float* shh = fb;          // 256 u32: h(s)[b,:] as packed f16 pairs
    float* p2l = fb + 512;    // 64    proj_e * LOG2E (my e-quarter)
    float* rzl = fb + 576;    // 64    1/Z_e
    float* tw = fb + 640;     // 128 u32: tw packed f16 pairs
    float* cp = fb + 896;     // [2][256] ctx partial reduce (fp32)

    // el in lane LOW bits (bank spread), kq in lane bits 3..5 (shfl 8/16/32)
    const int el = (tid & 7) | ((tid >> 6) << 3);  // e-local / t-quad (0..63)
    const int kq = (tid >> 3) & 7;                 // k-/t-eighth / e-group
    const int f = tid & 255, th = tid >> 8;        // ctx mapping

    // P0: full a[:,b,:] -> alds[f][t] as F16
    for (int i = tid; i < 65536; i += 512) {
      int t = i >> 8, ee = i & 255;
      alds[ee * 260 + t] = f2hbits(p.ali[t * 8192 + b * 256 + ee]);
    }
    if (tid == 0) {
      while (sysld32(p.bar) != FLAGS_MAGIC) __builtin_amdgcn_s_sleep(1);
    }
    p0bar(p.bar);
    // k-strided weight regs (f16 pairs): kp = i*8 + kq
    unsigned wr[32];
#pragma unroll
    for (int i = 0; i < 32; ++i) wr[i] = p.wattp[(i * 8 + kq) * 256 + q4 * 64 + el];

    for (int s = 0; s < 64; ++s) {
      // v20c poll placement: 32 lanes poll 32 hdone flags, then barrier.
      if (tid < 32) waitge(hdone + tid * 16, (unsigned)s);
      __syncthreads();
      // h(s)[b,:] -> shh as packed f16 pairs (plain cached read)
      if (tid < 128) {
        ull w = ((const ull*)(p.hbf + s * 16384 + b * 512))[tid];
        float f0 = btof((unsigned)(w & 0xffff));
        float f1 = btof((unsigned)((w >> 16) & 0xffff));
        float f2c = btof((unsigned)((w >> 32) & 0xffff));
        float f3 = btof((unsigned)((w >> 48) & 0xffff));
        unsigned* hp = (unsigned*)shh;
        hp[tid * 2] = pk2h(f0, f1);
        hp[tid * 2 + 1] = pk2h(f2c, f3);
      }
      __syncthreads();
      // proj (k-eighth, dot2) + Z (t-eighth) fused in-register, shfl 8/16/32
      {
        const unsigned* hp = (const unsigned*)shh;
        float a0 = 0.f, a1 = 0.f;
#pragma unroll
        for (int i = 0; i < 32; i += 2) {
          a0 = DOT2(as_h2(wr[i]), as_h2(hp[i * 8 + kq]), a0);
          a1 = DOT2(as_h2(wr[i + 1]), as_h2(hp[(i + 1) * 8 + kq]), a1);
        }
        float pr = a0 + a1;
        pr += __shfl_xor(pr, 8);
        pr += __shfl_xor(pr, 16);
        pr += __shfl_xor(pr, 32);
        const float pp = pr * LOG2E;
        // Z partial over my t-eighth (32 t)
        const unsigned short* ap = alds + (q4 * 64 + el) * 260 + kq * 32;
        float z0 = 0.f, z1 = 0.f;
#pragma unroll
        for (int j = 0; j < 8; ++j) {
          ushort4 v = *(const ushort4*)(ap + j * 4);
          z0 += EX2(h16tof(v.x) * pp) + EX2(h16tof(v.y) * pp);
          z1 += EX2(h16tof(v.z) * pp) + EX2(h16tof(v.w) * pp);
        }
        float zz = z0 + z1;
        zz += __shfl_xor(zz, 8);
        zz += __shfl_xor(zz, 16);
        zz += __shfl_xor(zz, 32);
        if (kq == 0) {
          p2l[el] = pp;
          rzl[el] = 1.0f / zz;
        }
      }
      __syncthreads();
      // pass2: tw_t = sum_e u/Z over my 64 e; shfl 8/16/32; writers pack f16
      {
        float t0 = 0.f, t1 = 0.f, t2 = 0.f, t3 = 0.f;
#pragma unroll
        for (int j = 0; j < 8; ++j) {
          const int e2 = kq * 8 + j;
          ushort4 v = *(const ushort4*)(alds + (q4 * 64 + e2) * 260 + el * 4);
          const float ppj = p2l[e2], rr = rzl[e2];
          t0 = fmaf(EX2(h16tof(v.x) * ppj), rr, t0);
          t1 = fmaf(EX2(h16tof(v.y) * ppj), rr, t1);
          t2 = fmaf(EX2(h16tof(v.z) * ppj), rr, t2);
          t3 = fmaf(EX2(h16tof(v.w) * ppj), rr, t3);
        }
        t0 += __shfl_xor(t0, 8); t0 += __shfl_xor(t0, 16); t0 += __shfl_xor(t0, 32);
        t1 += __shfl_xor(t1, 8); t1 += __shfl_xor(t1, 16); t1 += __shfl_xor(t1, 32);
        t2 += __shfl_xor(t2, 8); t2 += __shfl_xor(t2, 16); t2 += __shfl_xor(t2, 32);
        t3 += __shfl_xor(t3, 8); t3 += __shfl_xor(t3, 16); t3 += __shfl_xor(t3, 32);
        if (kq == 0) {
          unsigned* twp = (unsigned*)tw;
          twp[el * 2] = pk2h(t0, t1);
          twp[el * 2 + 1] = pk2h(t2, t3);
        }
      }
      __syncthreads();
      // ctx partial: ALL 256 f, t-half per th, dot2 (2 MAC/inst)
      {
        const unsigned short* ap = alds + f * 260 + th * 128;
        const unsigned* twv = (const unsigned*)tw + th * 64;
        float c0 = 0.f, c1 = 0.f;
#pragma unroll 4
        for (int j = 0; j < 32; ++j) {
          uint2 v = *(const uint2*)(ap + j * 4);
          c0 = DOT2(as_h2(v.x), as_h2(twv[2 * j]), c0);
          c1 = DOT2(as_h2(v.y), as_h2(twv[2 * j + 1]), c1);
        }
        cp[th * 256 + f] = c0 + c1;
      }
      __syncthreads();
      // FUSED publish: wave-0 lanes 0-31 pack + one dwordx4 store + per-wave
      // vmcnt drain; lane 0 posts flag. No trailing barrier (cp not rewritten
      // until >=3 barriers into the next step, which wave 0 joins).
      if (tid < 32) {
        const float4* cpa = (const float4*)cp + 2 * tid;
        const float4* cpb = (const float4*)(cp + 256) + 2 * tid;
        u32x4 u;
#pragma unroll
        for (int q = 0; q < 2; ++q) {
          float4 ca = cpa[q], cb = cpb[q];
          u[2 * q + 0] = (unsigned)f2bfbits(ca.x + cb.x) |
                         ((unsigned)f2bfbits(ca.y + cb.y) << 16);
          u[2 * q + 1] = (unsigned)f2bfbits(ca.z + cb.z) |
                         ((unsigned)f2bfbits(ca.w + cb.w) << 16);
        }
        sysst16_drain((unsigned*)(p.ctxb + (s * 128 + hb) * 256) + 4 * tid, u);
      }
      if (tid == 0) sysst32(ctxdone + hb * 16, (unsigned)(s + 1));
    }
  } else if (bid < 160) {
    // ============================ GRU path ============================
    const int dt = bid - 128;
    const int wv = tid >> 6;
    const bool act = wv < 6;
    const int l = tid & 63, lm = l & 15, lq = l >> 4;
    const int g = wv % 3, mt = wv / 3;
    const int am = mt * 16 + lm;
    const int brow = g * 512 + dt * 16 + lm;
    __hip_bfloat16* hA = (__hip_bfloat16*)smem;             // frag-major 32KB
    __hip_bfloat16* cA = (__hip_bfloat16*)(smem + 32768);   // frag-major 64KB (K=1024)
    float* pw = (float*)(smem + 98304);                     // [8][16][17]
    unsigned short* h16 = (unsigned short*)(smem + 107008); // [512]
    p0a_worker(p, (bid - 128) * 512 + tid);
    if (tid == 0) {
      while (sysld32(p.bar) != FLAGS_MAGIC) __builtin_amdgcn_s_sleep(1);
    }
    p0bar(p.bar);
    bf8 WH[16], WD[8], WC[8];
    if (act) {
#pragma unroll
      for (int kt = 0; kt < 16; ++kt) WH[kt] = ldfrag(p.whhb + brow * 512 + kt * 32 + lq * 8);
#pragma unroll
      for (int kt = 0; kt < 8; ++kt) WD[kt] = ldfrag(p.wihb + brow * 512 + kt * 32 + lq * 8);
#pragma unroll
      for (int kt = 0; kt < 8; ++kt) WC[kt] = ldfrag(p.wihb + brow * 512 + 256 + kt * 32 + lq * 8);
    }
    for (int s = 0; s < 64; ++s) {
      if (tid < 32) waitge(hdone + tid * 16, (unsigned)s);
      __syncthreads();
      stage_h_frag(hA, p.hbf + s * 16384, tid);
      __syncthreads();
      f32x4 acc = {0.f, 0.f, 0.f, 0.f};
      f32x4 gi = {0.f, 0.f, 0.f, 0.f};
      if (act) {
#pragma unroll
        for (int kt = 0; kt < 16; ++kt) {
          bf8 a = ldfrag(hA + (mt * 16 + kt) * 512 + l * 8);
          acc = MFMA16(a, WH[kt], acc);
        }
        const __hip_bfloat16* seqp = p.seqb + s * 8192;
#pragma unroll
        for (int kt = 0; kt < 8; ++kt) {
          bf8 a = ldfrag(seqp + am * 256 + kt * 32 + lq * 8);
          gi = MFMA16(a, WD[kt], gi);
        }
      }
      if (tid < 128) waitge(ctxdone + tid * 16, (unsigned)(s + 1));
      __syncthreads();
      stage_c4(cA, p.ctxb + s * 32768, tid);
      __syncthreads();
      if (act) {
        // gi_ctx over K=1024 concat quarters with duplicated W rows
#pragma unroll
        for (int kt = 0; kt < 32; ++kt) {
          bf8 a = ldfrag(cA + (mt * 32 + kt) * 512 + l * 8);
          gi = MFMA16(a, WC[kt & 7], gi);
        }
        if (g < 2) {
#pragma unroll
          for (int r = 0; r < 4; ++r) pw[(wv * 16 + lq * 4 + r) * 17 + lm] = acc[r] + gi[r];
        } else {
#pragma unroll
          for (int r = 0; r < 4; ++r) pw[(wv * 16 + lq * 4 + r) * 17 + lm] = acc[r];
#pragma unroll
          for (int r = 0; r < 4; ++r) pw[((6 + mt) * 16 + lq * 4 + r) * 17 + lm] = gi[r];
        }
      }
      __syncthreads();
      {
        const int bb = tid >> 4, dl = tid & 15;
        const int mtb = bb >> 4, bl = bb & 15;
        float rg = sigm(pw[((mtb * 3 + 0) * 16 + bl) * 17 + dl]);
        float zg = sigm(pw[((mtb * 3 + 1) * 16 + bl) * 17 + dl]);
        float hn = pw[((mtb * 3 + 2) * 16 + bl) * 17 + dl];
        float inn = pw[((6 + mtb) * 16 + bl) * 17 + dl];
        float nn = tanhfast(fmaf(rg, hn, inn));
        const int d = dt * 16 + dl;
        float ho = btof(((unsigned short*)hA)[((bb >> 4) * 16 + (d >> 5)) * 512 +
                                              (((d >> 3) & 3) * 16 + (bb & 15)) * 8 +
                                              (d & 7)]);
        float hnew = fmaxf(0.0f, fmaf(zg, ho - nn, nn));
        h16[bb * 16 + dl] = f2bfbits(hnew);
      }
      __syncthreads();
      // FUSED publish: wave 0 (64 lanes) x dwordx4 + per-wave drain; lane 0
      // posts flag. No trailing barrier (h16 not rewritten until >=3 barriers
      // into the next step, which wave 0 joins).
      if (tid < 64) {
        u32x4 hv = *(const u32x4*)(h16 + 8 * tid);
        sysst16_drain((unsigned*)(p.hbf + (s + 1) * 16384) +
                          (tid >> 1) * 256 + dt * 8 + (tid & 1) * 4,
                      hv);
      }
      if (tid == 0) sysst32(hdone + dt * 16, (unsigned)(s + 1));
    }
  } else {
    // ============================ MEL path ============================
    const int mt = bid - 160;  // batch half
    const int wv = tid >> 6;
    const bool act = wv < 6;
    const int l = tid & 63, lm = l & 15, lq = l >> 4;
    const int nt = wv;
    const int bn = nt * 16 + lm;
    __hip_bfloat16* hA = (__hip_bfloat16*)smem;
    __hip_bfloat16* cA = (__hip_bfloat16*)(smem + 32768);  // 64KB, K=1024
    p0a_worker(p, (bid - 128) * 512 + tid);
    if (tid == 0) {
      while (sysld32(p.bar) != FLAGS_MAGIC) __builtin_amdgcn_s_sleep(1);
    }
    p0bar(p.bar);
    bf8 WMC[8], WMH[16];
    float bias = 0.f;
    if (act) {
#pragma unroll
      for (int kt = 0; kt < 8; ++kt) WMC[kt] = ldfrag(p.wmelgb + bn * 768 + kt * 32 + lq * 8);
#pragma unroll
      for (int kt = 0; kt < 16; ++kt)
        WMH[kt] = ldfrag(p.wmelgb + bn * 768 + 256 + kt * 32 + lq * 8);
      bias = (bn < 80) ? p.bmel[bn] : ((bn == 80) ? p.bgate[0] : 0.f);
    }
    for (int tau = 0; tau < 64; ++tau) {
      if (tid < 32) waitge(hdone + tid * 16, (unsigned)(tau + 1));
      else if (tid >= 64 && tid < 192) waitge(ctxdone + (tid - 64) * 16, (unsigned)(tau + 1));
      __syncthreads();
      stage_h_frag(hA, p.hbf + (tau + 1) * 16384, tid);
      stage_c4(cA, p.ctxb + tau * 32768, tid);
      __syncthreads();
      if (act) {
        f32x4 acc = {0.f, 0.f, 0.f, 0.f};
#pragma unroll
        for (int kt = 0; kt < 48; ++kt) {
          bf8 a = (kt < 32) ? ldfrag(cA + (mt * 32 + kt) * 512 + l * 8)
                            : ldfrag(hA + (mt * 16 + (kt - 32)) * 512 + l * 8);
          bf8 bb2 = (kt < 32) ? WMC[kt & 7] : WMH[kt - 32];
          acc = MFMA16(a, bb2, acc);
        }
#pragma unroll
        for (int r = 0; r < 4; ++r) {
          int bb = mt * 16 + lq * 4 + r;
          float v = acc[r] + bias;
          if (bn < 80)
            p.out[bb * 5120 + bn * 64 + tau] = v;
          else if (bn == 80)
            p.out[163840 + bb * 64 + tau] = v;
        }
      }
      __syncthreads();
    }
  }
}

extern "C" void kernel_launch(void* const* d_in, const int* in_sizes, int n_in,
                              void* d_out, int out_size, void* d_ws, size_t ws_size,
                              hipStream_t stream) {
  Params P;
  P.dec = (const float*)d_in[0];
  P.ali = (const float*)d_in[1];
  P.watt = (const float*)d_in[2];
  P.wih = (const float*)d_in[3];
  P.whh = (const float*)d_in[4];
  P.wmel = (const float*)d_in[5];
  P.bmel = (const float*)d_in[6];
  P.wgate = (const float*)d_in[7];
  P.bgate = (const float*)d_in[8];
  P.out = (float*)d_out;

  char* w = (char*)d_ws;
  size_t o = 0;
  auto nxt = [&](size_t b) {
    char* r = w + o;
    o += (b + 255) & ~(size_t)255;
    return r;
  };
  P.bar = (unsigned*)nxt(16384);
  P.wihb = (__hip_bfloat16*)nxt(1536 * 512 * 2);
  P.whhb = (__hip_bfloat16*)nxt(1536 * 512 * 2);
  P.wmelgb = (__hip_bfloat16*)nxt(96 * 768 * 2);
  P.seqb = (__hip_bfloat16*)nxt(64 * 32 * 256 * 2);
  P.hbf = (__hip_bfloat16*)nxt(65 * 32 * 512 * 2);    // step-unique h ring
  P.ctxb = (__hip_bfloat16*)nxt(64 * 128 * 256 * 2);  // step-unique ctx ring
  P.wattp = (unsigned*)nxt(256 * 256 * 4);

  (void)hipFuncSetAttribute((const void*)rdec_kernel,
                            hipFuncAttributeMaxDynamicSharedMemorySize, SMEM_BYTES);

  void* args[] = {&P};
  hipError_t err = hipLaunchCooperativeKernel((void*)rdec_kernel, dim3(NBLK), dim3(512),
                                              args, SMEM_BYTES, stream);
  if (err != hipSuccess) {
    rdec_kernel<<<dim3(NBLK), dim3(512), SMEM_BYTES, stream>>>(P);
  }
}

// Round 16
// 782.956 us; speedup vs baseline: 1.0391x; 1.0388x over previous
//
#include <hip/hip_runtime.h>
#include <hip/hip_bf16.h>

// ============================================================================
// RecurrentDecoder v23 = v20c verbatim (the measured optimum: 690us steady /
// 777us reported). v22's bisect showed the fused publish drain itself
// regresses (+0.6us/step): v20c's publish -> __syncthreads(drain) -> flag
// choreography beats every variation tried (v16/v21/v22). Plateau constraint:
// 64 serial steps x {2 inter-XCD visibility hops (~2.5-3us each, insensitive
// to traffic/width/discovery-fusion per v17/v18/v19) + ~2.5us att compute
// (dot2-packed; exp2 core irreducible) + ~1.5us GRU/mel}. No HW resource
// near roof (HBM 1.2%, MFMA 0.65%, VALU 13.8%) -- latency-bound recurrence.
// Structure: 162 blocks. ATT 0..127 (batch b x e-quarter q4): block-local
// softmax over t, f16 dot2 datapath, partial-ctx quarters published bf16.
// GRU 128..159 (d-slice, weights in VGPRs, K=1024 ctx MFMA with WC[kt&7]).
// MEL 160..161. Step-unique hbf[65]/ctxb[64] (plain cached consumer reads,
// sc0sc1 write-through publishes), 32-lane flag polls + s_sleep, shfl
// 8/16/32 in-register reductions.
// ============================================================================

#define LOG2E 1.4426950408889634f
#define FLAGS_MAGIC 0x13572468u
#define SMEM_BYTES 138752
#define NBLK 162

typedef __attribute__((ext_vector_type(8))) short bf8;
typedef __attribute__((ext_vector_type(4))) float f32x4;
typedef __attribute__((ext_vector_type(4))) unsigned u32x4;
typedef __attribute__((ext_vector_type(2))) __fp16 h2f;  // matches builtin V2h
typedef unsigned long long ull;

#define EX2(x) exp2f(x)
#define MFMA16(a, b, c) __builtin_amdgcn_mfma_f32_16x16x32_bf16(a, b, c, 0, 0, 0)

struct Params {
  const float* dec;
  const float* ali;
  const float* watt;
  const float* wih;
  const float* whh;
  const float* wmel;
  const float* bmel;
  const float* wgate;
  const float* bgate;
  float* out;
  unsigned* bar;  // [0]=magic [16]=p0cnt [32+16i]=hdone(32) [544+16j]=ctxdone(128)
  __hip_bfloat16* wihb;    // [1536][512]
  __hip_bfloat16* whhb;    // [1536][512]
  __hip_bfloat16* wmelgb;  // [96][768]
  __hip_bfloat16* seqb;    // [64][32][256]
  __hip_bfloat16* hbf;     // [65][32][512]   slot s = h(s), step-unique
  __hip_bfloat16* ctxb;    // [64][128][256]  slot s = ctx(s) (hb = q4*32+b)
  unsigned* wattp;         // [256][256] packed F16 pairs of W_att^T
};

__device__ __forceinline__ bf8 ldfrag(const __hip_bfloat16* p) { return *(const bf8*)p; }
__device__ __forceinline__ float sigm(float x) { return 1.0f / (1.0f + EX2(-x * LOG2E)); }
__device__ __forceinline__ float tanhfast(float x) {
  x = fminf(fmaxf(x, -15.0f), 15.0f);
  float e = EX2(x * (2.0f * LOG2E));
  return (e - 1.0f) / (e + 1.0f);
}
__device__ __forceinline__ float btof(unsigned v) { return __uint_as_float(v << 16); }
__device__ __forceinline__ unsigned short f2bfbits(float x) {
  __hip_bfloat16 h = __float2bfloat16(x);
  return *(unsigned short*)&h;
}
// f16 helpers (att datapath)
__device__ __forceinline__ unsigned short f2hbits(float x) {
  __fp16 h = (__fp16)x;
  return *(unsigned short*)&h;
}
__device__ __forceinline__ float h16tof(unsigned short u) {
  __fp16 h;
  *(unsigned short*)&h = u;
  return (float)h;
}
__device__ __forceinline__ h2f as_h2(unsigned u) {
  union { unsigned u; h2f h; } c;
  c.u = u;
  return c.h;
}
__device__ __forceinline__ unsigned pk2h(float a, float b) {
  union { h2f h; unsigned u; } c;
  c.h = __builtin_amdgcn_cvt_pkrtz(a, b);
  return c.u;
}
#define DOT2(a, b, c) __builtin_amdgcn_fdot2((a), (b), (c), false)

__device__ __forceinline__ unsigned sysld32(const unsigned* p) {
  return __hip_atomic_load(p, __ATOMIC_RELAXED, __HIP_MEMORY_SCOPE_SYSTEM);
}
__device__ __forceinline__ void sysst32(unsigned* p, unsigned v) {
  __hip_atomic_store(p, v, __ATOMIC_RELAXED, __HIP_MEMORY_SCOPE_SYSTEM);
}
// Wide write-through store (16B). Drained by the following __syncthreads'
// compiler-emitted s_waitcnt vmcnt(0) before the flag posts.
__device__ __forceinline__ void sysst16(void* dst, u32x4 v) {
  asm volatile("global_store_dwordx4 %0, %1, off sc0 sc1"
               :: "v"(dst), "v"(v) : "memory");
}
__device__ __forceinline__ void waitge(unsigned* w, unsigned tgt) {
  while (sysld32(w) < tgt) __builtin_amdgcn_s_sleep(1);
}

__device__ __forceinline__ void p0bar(unsigned* bar) {
  __syncthreads();
  if (threadIdx.x == 0) {
    __builtin_amdgcn_fence(__ATOMIC_RELEASE, "agent");
    __hip_atomic_fetch_add(bar + 16, 1u, __ATOMIC_RELAXED, __HIP_MEMORY_SCOPE_SYSTEM);
    while (sysld32(bar + 16) < (unsigned)NBLK) __builtin_amdgcn_s_sleep(1);
    __builtin_amdgcn_fence(__ATOMIC_ACQUIRE, "agent");
  }
  __syncthreads();
}

// P0 conversion work for blocks 128..161 (wid in [0, 34*512))
__device__ __forceinline__ void p0a_worker(const Params& p, int wid) {
  for (int i = wid; i < 2252800; i += 17408) {
    if (i < 786432) {
      p.wihb[i] = __float2bfloat16(p.wih[i]);
    } else if (i < 1572864) {
      int j = i - 786432;
      p.whhb[j] = __float2bfloat16(p.whh[j]);
    } else if (i < 2097152) {
      int j = i - 1572864;
      int s = j >> 13;
      p.seqb[j] = (s == 0) ? __float2bfloat16(0.0f) : __float2bfloat16(p.dec[j - 8192]);
    } else if (i < 2170880) {
      int j = i - 2097152;
      int r = j / 768, c = j - r * 768;
      float v = (r < 80) ? p.wmel[j] : ((r == 80) ? p.wgate[c] : 0.0f);
      p.wmelgb[j] = __float2bfloat16(v);
    } else if (i < 2236416) {
      int j = i - 2170880;
      int kp = j >> 8, e = j & 255;
      unsigned lo = f2hbits(p.watt[e * 512 + 2 * kp]);
      unsigned hi = f2hbits(p.watt[e * 512 + 2 * kp + 1]);
      p.wattp[j] = lo | (hi << 16);
    } else {
      int j = i - 2236416;
      p.hbf[j] = __float2bfloat16(0.0f);  // hbf slot 0 = h(0) = 0
    }
  }
}

// Stage h[32][512] (row-major, PLAIN cached loads) into fragment-major LDS.
__device__ __forceinline__ void stage_h_frag(__hip_bfloat16* hA,
                                             const __hip_bfloat16* hsrc, int tid) {
  const int lm = tid & 15, lq = (tid >> 4) & 3, wq = tid >> 6;
  const int dst_in = (lq * 16 + lm) * 8;
  const int i0 = wq, i1 = 8 + wq, i2 = 16 + wq, i3 = 24 + wq;
  auto soff = [&](int idx) {
    return ((idx >> 4) * 16 + lm) * 512 + (idx & 15) * 32 + lq * 8;
  };
  u32x4 a = *(const u32x4*)(hsrc + soff(i0));
  u32x4 b = *(const u32x4*)(hsrc + soff(i1));
  u32x4 c = *(const u32x4*)(hsrc + soff(i2));
  u32x4 d = *(const u32x4*)(hsrc + soff(i3));
  u32x4* dst = (u32x4*)hA;
  dst[(i0 * 512 + dst_in) >> 3] = a;
  dst[(i1 * 512 + dst_in) >> 3] = b;
  dst[(i2 * 512 + dst_in) >> 3] = c;
  dst[(i3 * 512 + dst_in) >> 3] = d;
}
// Stage concat-ctx [b, k=q4*256+e] (src slot: [128][256], hb=q4*32+b) into
// fragment-major LDS (64 sections over K=1024). PLAIN cached loads.
__device__ __forceinline__ void stage_c4(__hip_bfloat16* cA,
                                         const __hip_bfloat16* csrc, int tid) {
  const int lm = tid & 15, lq = (tid >> 4) & 3, wq = tid >> 6;
  const int dst_in = (lq * 16 + lm) * 8;
  u32x4* dst = (u32x4*)cA;
  auto soff = [&](int idx) {
    int mt = idx >> 5, kt = idx & 31;
    int bb = mt * 16 + lm;
    int k = kt * 32 + lq * 8;
    return ((k >> 8) * 32 + bb) * 256 + (k & 255);
  };
#pragma unroll
  for (int r = 0; r < 8; ++r) {
    const int idx = r * 8 + wq;
    u32x4 v = *(const u32x4*)(csrc + soff(idx));
    dst[(idx * 512 + dst_in) >> 3] = v;
  }
}

__global__ void __launch_bounds__(512, 1) rdec_kernel(Params p) {
  const int tid = threadIdx.x;
  const int bid = blockIdx.x;
  extern __shared__ char smem[];
  unsigned* hdone = p.bar + 32;     // 32 flags
  unsigned* ctxdone = p.bar + 544;  // 128 flags

  if (bid == 0) {
    for (int i = 1 + tid; i < 2624; i += 512) sysst32(p.bar + i, 0u);
    __syncthreads();
    if (tid == 0) sysst32(p.bar, FLAGS_MAGIC);
  }

  if (bid < 128) {
    // =================== ATT path (batch b, e-quarter q4) ===================
    const int b = bid >> 2, q4 = bid & 3, hb = q4 * 32 + b;
    unsigned short* alds = (unsigned short*)smem;  // [256 f][260 t] F16 (pad)
    float* fb = (float*)(smem + 133120);
    float* shh = fb;          // 256 u32: h(s)[b,:] as packed f16 pairs
    float* p2l = fb + 512;    // 64    proj_e * LOG2E (my e-quarter)
    float* rzl = fb + 576;    // 64    1/Z_e
    float* tw = fb + 640;     // 128 u32: tw packed f16 pairs
    float* cp = fb + 896;     // [2][256] ctx partial reduce (fp32)

    // el in lane LOW bits (bank spread), kq in lane bits 3..5 (shfl 8/16/32)
    const int el = (tid & 7) | ((tid >> 6) << 3);  // e-local / t-quad (0..63)
    const int kq = (tid >> 3) & 7;                 // k-/t-eighth / e-group
    const int f = tid & 255, th = tid >> 8;        // ctx mapping

    // P0: full a[:,b,:] -> alds[f][t] as F16
    for (int i = tid; i < 65536; i += 512) {
      int t = i >> 8, ee = i & 255;
      alds[ee * 260 + t] = f2hbits(p.ali[t * 8192 + b * 256 + ee]);
    }
    if (tid == 0) {
      while (sysld32(p.bar) != FLAGS_MAGIC) __builtin_amdgcn_s_sleep(1);
    }
    p0bar(p.bar);
    // k-strided weight regs (f16 pairs): kp = i*8 + kq
    unsigned wr[32];
#pragma unroll
    for (int i = 0; i < 32; ++i) wr[i] = p.wattp[(i * 8 + kq) * 256 + q4 * 64 + el];

    for (int s = 0; s < 64; ++s) {
      if (tid < 32) waitge(hdone + tid * 16, (unsigned)s);
      __syncthreads();
      // h(s)[b,:] -> shh as packed f16 pairs (plain cached read)
      if (tid < 128) {
        ull w = ((const ull*)(p.hbf + s * 16384 + b * 512))[tid];
        float f0 = btof((unsigned)(w & 0xffff));
        float f1 = btof((unsigned)((w >> 16) & 0xffff));
        float f2c = btof((unsigned)((w >> 32) & 0xffff));
        float f3 = btof((unsigned)((w >> 48) & 0xffff));
        unsigned* hp = (unsigned*)shh;
        hp[tid * 2] = pk2h(f0, f1);
        hp[tid * 2 + 1] = pk2h(f2c, f3);
      }
      __syncthreads();
      // proj (k-eighth, dot2) + Z (t-eighth) fused in-register, shfl 8/16/32
      {
        const unsigned* hp = (const unsigned*)shh;
        float a0 = 0.f, a1 = 0.f;
#pragma unroll
        for (int i = 0; i < 32; i += 2) {
          a0 = DOT2(as_h2(wr[i]), as_h2(hp[i * 8 + kq]), a0);
          a1 = DOT2(as_h2(wr[i + 1]), as_h2(hp[(i + 1) * 8 + kq]), a1);
        }
        float pr = a0 + a1;
        pr += __shfl_xor(pr, 8);
        pr += __shfl_xor(pr, 16);
        pr += __shfl_xor(pr, 32);
        const float pp = pr * LOG2E;
        // Z partial over my t-eighth (32 t)
        const unsigned short* ap = alds + (q4 * 64 + el) * 260 + kq * 32;
        float z0 = 0.f, z1 = 0.f;
#pragma unroll
        for (int j = 0; j < 8; ++j) {
          ushort4 v = *(const ushort4*)(ap + j * 4);
          z0 += EX2(h16tof(v.x) * pp) + EX2(h16tof(v.y) * pp);
          z1 += EX2(h16tof(v.z) * pp) + EX2(h16tof(v.w) * pp);
        }
        float zz = z0 + z1;
        zz += __shfl_xor(zz, 8);
        zz += __shfl_xor(zz, 16);
        zz += __shfl_xor(zz, 32);
        if (kq == 0) {
          p2l[el] = pp;
          rzl[el] = 1.0f / zz;
        }
      }
      __syncthreads();
      // pass2: tw_t = sum_e u/Z over my 64 e; shfl 8/16/32; writers pack f16
      {
        float t0 = 0.f, t1 = 0.f, t2 = 0.f, t3 = 0.f;
#pragma unroll
        for (int j = 0; j < 8; ++j) {
          const int e2 = kq * 8 + j;
          ushort4 v = *(const ushort4*)(alds + (q4 * 64 + e2) * 260 + el * 4);
          const float ppj = p2l[e2], rr = rzl[e2];
          t0 = fmaf(EX2(h16tof(v.x) * ppj), rr, t0);
          t1 = fmaf(EX2(h16tof(v.y) * ppj), rr, t1);
          t2 = fmaf(EX2(h16tof(v.z) * ppj), rr, t2);
          t3 = fmaf(EX2(h16tof(v.w) * ppj), rr, t3);
        }
        t0 += __shfl_xor(t0, 8); t0 += __shfl_xor(t0, 16); t0 += __shfl_xor(t0, 32);
        t1 += __shfl_xor(t1, 8); t1 += __shfl_xor(t1, 16); t1 += __shfl_xor(t1, 32);
        t2 += __shfl_xor(t2, 8); t2 += __shfl_xor(t2, 16); t2 += __shfl_xor(t2, 32);
        t3 += __shfl_xor(t3, 8); t3 += __shfl_xor(t3, 16); t3 += __shfl_xor(t3, 32);
        if (kq == 0) {
          unsigned* twp = (unsigned*)tw;
          twp[el * 2] = pk2h(t0, t1);
          twp[el * 2 + 1] = pk2h(t2, t3);
        }
      }
      __syncthreads();
      // ctx partial: ALL 256 f, t-half per th, dot2 (2 MAC/inst)
      {
        const unsigned short* ap = alds + f * 260 + th * 128;
        const unsigned* twv = (const unsigned*)tw + th * 64;
        float c0 = 0.f, c1 = 0.f;
#pragma unroll 4
        for (int j = 0; j < 32; ++j) {
          uint2 v = *(const uint2*)(ap + j * 4);
          c0 = DOT2(as_h2(v.x), as_h2(twv[2 * j]), c0);
          c1 = DOT2(as_h2(v.y), as_h2(twv[2 * j + 1]), c1);
        }
        cp[th * 256 + f] = c0 + c1;
      }
      __syncthreads();
      // WIDE publish: 32 lanes combine 8 f each, one dwordx4 write-through.
      if (tid < 32) {
        const float4* cpa = (const float4*)cp + 2 * tid;
        const float4* cpb = (const float4*)(cp + 256) + 2 * tid;
        u32x4 u;
#pragma unroll
        for (int q = 0; q < 2; ++q) {
          float4 ca = cpa[q], cb = cpb[q];
          u[2 * q + 0] = (unsigned)f2bfbits(ca.x + cb.x) |
                         ((unsigned)f2bfbits(ca.y + cb.y) << 16);
          u[2 * q + 1] = (unsigned)f2bfbits(ca.z + cb.z) |
                         ((unsigned)f2bfbits(ca.w + cb.w) << 16);
        }
        sysst16((unsigned*)(p.ctxb + (s * 128 + hb) * 256) + 4 * tid, u);
      }
      __syncthreads();  // drains wave0's publish stores (vmcnt(0) at barrier)
      if (tid == 0) sysst32(ctxdone + hb * 16, (unsigned)(s + 1));
    }
  } else if (bid < 160) {
    // ============================ GRU path ============================
    const int dt = bid - 128;
    const int wv = tid >> 6;
    const bool act = wv < 6;
    const int l = tid & 63, lm = l & 15, lq = l >> 4;
    const int g = wv % 3, mt = wv / 3;
    const int am = mt * 16 + lm;
    const int brow = g * 512 + dt * 16 + lm;
    __hip_bfloat16* hA = (__hip_bfloat16*)smem;             // frag-major 32KB
    __hip_bfloat16* cA = (__hip_bfloat16*)(smem + 32768);   // frag-major 64KB (K=1024)
    float* pw = (float*)(smem + 98304);                     // [8][16][17]
    unsigned short* h16 = (unsigned short*)(smem + 107008); // [512]
    p0a_worker(p, (bid - 128) * 512 + tid);
    if (tid == 0) {
      while (sysld32(p.bar) != FLAGS_MAGIC) __builtin_amdgcn_s_sleep(1);
    }
    p0bar(p.bar);
    bf8 WH[16], WD[8], WC[8];
    if (act) {
#pragma unroll
      for (int kt = 0; kt < 16; ++kt) WH[kt] = ldfrag(p.whhb + brow * 512 + kt * 32 + lq * 8);
#pragma unroll
      for (int kt = 0; kt < 8; ++kt) WD[kt] = ldfrag(p.wihb + brow * 512 + kt * 32 + lq * 8);
#pragma unroll
      for (int kt = 0; kt < 8; ++kt) WC[kt] = ldfrag(p.wihb + brow * 512 + 256 + kt * 32 + lq * 8);
    }
    for (int s = 0; s < 64; ++s) {
      if (tid < 32) waitge(hdone + tid * 16, (unsigned)s);
      __syncthreads();
      stage_h_frag(hA, p.hbf + s * 16384, tid);
      __syncthreads();
      f32x4 acc = {0.f, 0.f, 0.f, 0.f};
      f32x4 gi = {0.f, 0.f, 0.f, 0.f};
      if (act) {
#pragma unroll
        for (int kt = 0; kt < 16; ++kt) {
          bf8 a = ldfrag(hA + (mt * 16 + kt) * 512 + l * 8);
          acc = MFMA16(a, WH[kt], acc);
        }
        const __hip_bfloat16* seqp = p.seqb + s * 8192;
#pragma unroll
        for (int kt = 0; kt < 8; ++kt) {
          bf8 a = ldfrag(seqp + am * 256 + kt * 32 + lq * 8);
          gi = MFMA16(a, WD[kt], gi);
        }
      }
      if (tid < 128) waitge(ctxdone + tid * 16, (unsigned)(s + 1));
      __syncthreads();
      stage_c4(cA, p.ctxb + s * 32768, tid);
      __syncthreads();
      if (act) {
        // gi_ctx over K=1024 concat quarters with duplicated W rows
#pragma unroll
        for (int kt = 0; kt < 32; ++kt) {
          bf8 a = ldfrag(cA + (mt * 32 + kt) * 512 + l * 8);
          gi = MFMA16(a, WC[kt & 7], gi);
        }
        if (g < 2) {
#pragma unroll
          for (int r = 0; r < 4; ++r) pw[(wv * 16 + lq * 4 + r) * 17 + lm] = acc[r] + gi[r];
        } else {
#pragma unroll
          for (int r = 0; r < 4; ++r) pw[(wv * 16 + lq * 4 + r) * 17 + lm] = acc[r];
#pragma unroll
          for (int r = 0; r < 4; ++r) pw[((6 + mt) * 16 + lq * 4 + r) * 17 + lm] = gi[r];
        }
      }
      __syncthreads();
      {
        const int bb = tid >> 4, dl = tid & 15;
        const int mtb = bb >> 4, bl = bb & 15;
        float rg = sigm(pw[((mtb * 3 + 0) * 16 + bl) * 17 + dl]);
        float zg = sigm(pw[((mtb * 3 + 1) * 16 + bl) * 17 + dl]);
        float hn = pw[((mtb * 3 + 2) * 16 + bl) * 17 + dl];
        float inn = pw[((6 + mtb) * 16 + bl) * 17 + dl];
        float nn = tanhfast(fmaf(rg, hn, inn));
        const int d = dt * 16 + dl;
        float ho = btof(((unsigned short*)hA)[((bb >> 4) * 16 + (d >> 5)) * 512 +
                                              (((d >> 3) & 3) * 16 + (bb & 15)) * 8 +
                                              (d & 7)]);
        float hnew = fmaxf(0.0f, fmaf(zg, ho - nn, nn));
        h16[bb * 16 + dl] = f2bfbits(hnew);
      }
      __syncthreads();
      // WIDE publish: 64 lanes x dwordx4 write-through of h(s+1) slice.
      if (tid < 64) {
        u32x4 hv = *(const u32x4*)(h16 + 8 * tid);
        sysst16((unsigned*)(p.hbf + (s + 1) * 16384) +
                    (tid >> 1) * 256 + dt * 8 + (tid & 1) * 4,
                hv);
      }
      __syncthreads();  // drains wave0's publish stores (vmcnt(0) at barrier)
      if (tid == 0) sysst32(hdone + dt * 16, (unsigned)(s + 1));
    }
  } else {
    // ============================ MEL path ============================
    const int mt = bid - 160;  // batch half
    const int wv = tid >> 6;
    const bool act = wv < 6;
    const int l = tid & 63, lm = l & 15, lq = l >> 4;
    const int nt = wv;
    const int bn = nt * 16 + lm;
    __hip_bfloat16* hA = (__hip_bfloat16*)smem;
    __hip_bfloat16* cA = (__hip_bfloat16*)(smem + 32768);  // 64KB, K=1024
    p0a_worker(p, (bid - 128) * 512 + tid);
    if (tid == 0) {
      while (sysld32(p.bar) != FLAGS_MAGIC) __builtin_amdgcn_s_sleep(1);
    }
    p0bar(p.bar);
    bf8 WMC[8], WMH[16];
    float bias = 0.f;
    if (act) {
#pragma unroll
      for (int kt = 0; kt < 8; ++kt) WMC[kt] = ldfrag(p.wmelgb + bn * 768 + kt * 32 + lq * 8);
#pragma unroll
      for (int kt = 0; kt < 16; ++kt)
        WMH[kt] = ldfrag(p.wmelgb + bn * 768 + 256 + kt * 32 + lq * 8);
      bias = (bn < 80) ? p.bmel[bn] : ((bn == 80) ? p.bgate[0] : 0.f);
    }
    for (int tau = 0; tau < 64; ++tau) {
      if (tid < 32) waitge(hdone + tid * 16, (unsigned)(tau + 1));
      else if (tid >= 64 && tid < 192) waitge(ctxdone + (tid - 64) * 16, (unsigned)(tau + 1));
      __syncthreads();
      stage_h_frag(hA, p.hbf + (tau + 1) * 16384, tid);
      stage_c4(cA, p.ctxb + tau * 32768, tid);
      __syncthreads();
      if (act) {
        f32x4 acc = {0.f, 0.f, 0.f, 0.f};
#pragma unroll
        for (int kt = 0; kt < 48; ++kt) {
          bf8 a = (kt < 32) ? ldfrag(cA + (mt * 32 + kt) * 512 + l * 8)
                            : ldfrag(hA + (mt * 16 + (kt - 32)) * 512 + l * 8);
          bf8 bb2 = (kt < 32) ? WMC[kt & 7] : WMH[kt - 32];
          acc = MFMA16(a, bb2, acc);
        }
#pragma unroll
        for (int r = 0; r < 4; ++r) {
          int bb = mt * 16 + lq * 4 + r;
          float v = acc[r] + bias;
          if (bn < 80)
            p.out[bb * 5120 + bn * 64 + tau] = v;
          else if (bn == 80)
            p.out[163840 + bb * 64 + tau] = v;
        }
      }
      __syncthreads();
    }
  }
}

extern "C" void kernel_launch(void* const* d_in, const int* in_sizes, int n_in,
                              void* d_out, int out_size, void* d_ws, size_t ws_size,
                              hipStream_t stream) {
  Params P;
  P.dec = (const float*)d_in[0];
  P.ali = (const float*)d_in[1];
  P.watt = (const float*)d_in[2];
  P.wih = (const float*)d_in[3];
  P.whh = (const float*)d_in[4];
  P.wmel = (const float*)d_in[5];
  P.bmel = (const float*)d_in[6];
  P.wgate = (const float*)d_in[7];
  P.bgate = (const float*)d_in[8];
  P.out = (float*)d_out;

  char* w = (char*)d_ws;
  size_t o = 0;
  auto nxt = [&](size_t b) {
    char* r = w + o;
    o += (b + 255) & ~(size_t)255;
    return r;
  };
  P.bar = (unsigned*)nxt(16384);
  P.wihb = (__hip_bfloat16*)nxt(1536 * 512 * 2);
  P.whhb = (__hip_bfloat16*)nxt(1536 * 512 * 2);
  P.wmelgb = (__hip_bfloat16*)nxt(96 * 768 * 2);
  P.seqb = (__hip_bfloat16*)nxt(64 * 32 * 256 * 2);
  P.hbf = (__hip_bfloat16*)nxt(65 * 32 * 512 * 2);    // step-unique h ring
  P.ctxb = (__hip_bfloat16*)nxt(64 * 128 * 256 * 2);  // step-unique ctx ring
  P.wattp = (unsigned*)nxt(256 * 256 * 4);

  (void)hipFuncSetAttribute((const void*)rdec_kernel,
                            hipFuncAttributeMaxDynamicSharedMemorySize, SMEM_BYTES);

  void* args[] = {&P};
  hipError_t err = hipLaunchCooperativeKernel((void*)rdec_kernel, dim3(NBLK), dim3(512),
                                              args, SMEM_BYTES, stream);
  if (err != hipSuccess) {
    rdec_kernel<<<dim3(NBLK), dim3(512), SMEM_BYTES, stream>>>(P);
  }
}